// Round 6
// baseline (358.780 us; speedup 1.0000x reference)
//
#include <hip/hip_runtime.h>

#define H_ 160
#define W_ 160
#define CIN 32
#define COUT 32
#define HW_ (H_ * W_)
#define NPIX (8 * HW_)   // 204800 pixels total

// ============================================================================
// R6: NHWC gathers + 2-way channel split.
//  - nhwc_transpose: x (B,C,H,W) -> xT (B,H,W,C) in d_ws. All later gathers
//    become float4 loads with immediate offsets (R5 was 4B-per-instr scalar
//    gathers, VGPR=52 -> compiler serialized loads, VALUBusy 22%).
//  - both conv kernels: 2 threads/pixel (16 input channels each, xor-32
//    reduce) -> 2x waves for latency hiding. No XCD swizzle (R4 regression).
//  - tap loops rolled (#pragma unroll 1): small I-footprint; per-tap FMA
//    burst (~500cy) hides L2 latency; named-scalar accumulators only.
// ============================================================================

__global__ __launch_bounds__(256) void nhwc_transpose(
    const float* __restrict__ x, float* __restrict__ xT)
{
    const int pix = blockIdx.x * 256 + threadIdx.x;
    const int p = pix % HW_;
    const int b = pix / HW_;
    const float* __restrict__ src = x + (size_t)b * CIN * HW_ + p;
    float* __restrict__ dst = xT + (size_t)pix * CIN;
    #pragma unroll
    for (int g = 0; g < 8; ++g) {
        float4 o;
        o.x = src[(4 * g + 0) * HW_];
        o.y = src[(4 * g + 1) * HW_];
        o.z = src[(4 * g + 2) * HW_];
        o.w = src[(4 * g + 3) * HW_];
        *(float4*)(dst + 4 * g) = o;
    }
}

// ---------------- Kernel A: 3x3 offset conv (Cin=32 -> 18 channels) --------
// block = 256 threads = 128 pixels x 2 channel-halves (sub = lane>>5).
__global__ __launch_bounds__(256, 4) void dcn_offset(
    const float* __restrict__ xT,     // (8, 160, 160, 32)
    const float* __restrict__ w_off,  // (18, 32, 3, 3)
    const float* __restrict__ b_off,  // (18,)
    float* __restrict__ off_ws)       // [18][NPIX]
{
    __shared__ __align__(16) float wl[9 * 18 * 32];  // [tap][j][c]
    __shared__ float bl[18];
    const int tid = threadIdx.x;
    for (int d = tid; d < 9 * 18 * 32; d += 256) {
        int tap = d / 576, j = (d / 32) % 18, c = d & 31;
        wl[d] = w_off[(j * 32 + c) * 9 + tap];
    }
    if (tid < 18) bl[tid] = b_off[tid];
    __syncthreads();

    const int lane = tid & 63;
    const int sub = lane >> 5;                      // 0..1 -> channels sub*16..
    const int pl = (tid >> 6) * 32 + (lane & 31);   // 0..127
    const int pix = blockIdx.x * 128 + pl;
    const int w = pix % W_;
    const int h = (pix / W_) % H_;
    const int b = pix / HW_;
    const float* __restrict__ xb = xT + (size_t)b * HW_ * CIN + sub * 16;

    float a0 = 0, a1 = 0, a2 = 0, a3 = 0, a4 = 0, a5 = 0, a6 = 0, a7 = 0, a8 = 0;
    float a9 = 0, a10 = 0, a11 = 0, a12 = 0, a13 = 0, a14 = 0, a15 = 0, a16 = 0, a17 = 0;

    #define DOT16(acc, wp) { \
        const float4 q0 = ((const float4*)(wp))[0]; \
        const float4 q1 = ((const float4*)(wp))[1]; \
        const float4 q2 = ((const float4*)(wp))[2]; \
        const float4 q3 = ((const float4*)(wp))[3]; \
        acc = fmaf(vA0.x, q0.x, acc); acc = fmaf(vA0.y, q0.y, acc); \
        acc = fmaf(vA0.z, q0.z, acc); acc = fmaf(vA0.w, q0.w, acc); \
        acc = fmaf(vA1.x, q1.x, acc); acc = fmaf(vA1.y, q1.y, acc); \
        acc = fmaf(vA1.z, q1.z, acc); acc = fmaf(vA1.w, q1.w, acc); \
        acc = fmaf(vA2.x, q2.x, acc); acc = fmaf(vA2.y, q2.y, acc); \
        acc = fmaf(vA2.z, q2.z, acc); acc = fmaf(vA2.w, q2.w, acc); \
        acc = fmaf(vA3.x, q3.x, acc); acc = fmaf(vA3.y, q3.y, acc); \
        acc = fmaf(vA3.z, q3.z, acc); acc = fmaf(vA3.w, q3.w, acc); }

    #pragma unroll 1
    for (int tap = 0; tap < 9; ++tap) {
        const int yy = h - 1 + tap / 3;
        const int xx = w - 1 + tap % 3;
        const bool valid = (yy >= 0) && (yy < H_) && (xx >= 0) && (xx < W_);
        const int idx = min(max(yy, 0), H_ - 1) * W_ + min(max(xx, 0), W_ - 1);
        const float m = valid ? 1.0f : 0.0f;
        const float* __restrict__ pv = xb + (size_t)idx * CIN;
        float4 vA0 = ((const float4*)pv)[0];
        float4 vA1 = ((const float4*)pv)[1];
        float4 vA2 = ((const float4*)pv)[2];
        float4 vA3 = ((const float4*)pv)[3];
        vA0.x *= m; vA0.y *= m; vA0.z *= m; vA0.w *= m;
        vA1.x *= m; vA1.y *= m; vA1.z *= m; vA1.w *= m;
        vA2.x *= m; vA2.y *= m; vA2.z *= m; vA2.w *= m;
        vA3.x *= m; vA3.y *= m; vA3.z *= m; vA3.w *= m;
        const float* __restrict__ wt = &wl[tap * 576 + sub * 16];
        DOT16(a0,  wt + 0 * 32);   DOT16(a1,  wt + 1 * 32);
        DOT16(a2,  wt + 2 * 32);   DOT16(a3,  wt + 3 * 32);
        DOT16(a4,  wt + 4 * 32);   DOT16(a5,  wt + 5 * 32);
        DOT16(a6,  wt + 6 * 32);   DOT16(a7,  wt + 7 * 32);
        DOT16(a8,  wt + 8 * 32);   DOT16(a9,  wt + 9 * 32);
        DOT16(a10, wt + 10 * 32);  DOT16(a11, wt + 11 * 32);
        DOT16(a12, wt + 12 * 32);  DOT16(a13, wt + 13 * 32);
        DOT16(a14, wt + 14 * 32);  DOT16(a15, wt + 15 * 32);
        DOT16(a16, wt + 16 * 32);  DOT16(a17, wt + 17 * 32);
    }
    #undef DOT16

    a0  += __shfl_xor(a0, 32);  a1  += __shfl_xor(a1, 32);
    a2  += __shfl_xor(a2, 32);  a3  += __shfl_xor(a3, 32);
    a4  += __shfl_xor(a4, 32);  a5  += __shfl_xor(a5, 32);
    a6  += __shfl_xor(a6, 32);  a7  += __shfl_xor(a7, 32);
    a8  += __shfl_xor(a8, 32);  a9  += __shfl_xor(a9, 32);
    a10 += __shfl_xor(a10, 32); a11 += __shfl_xor(a11, 32);
    a12 += __shfl_xor(a12, 32); a13 += __shfl_xor(a13, 32);
    a14 += __shfl_xor(a14, 32); a15 += __shfl_xor(a15, 32);
    a16 += __shfl_xor(a16, 32); a17 += __shfl_xor(a17, 32);

    if (sub == 0) {
        off_ws[0 * NPIX + pix] = a0 + bl[0];
        off_ws[1 * NPIX + pix] = a1 + bl[1];
        off_ws[2 * NPIX + pix] = a2 + bl[2];
        off_ws[3 * NPIX + pix] = a3 + bl[3];
        off_ws[4 * NPIX + pix] = a4 + bl[4];
        off_ws[5 * NPIX + pix] = a5 + bl[5];
        off_ws[6 * NPIX + pix] = a6 + bl[6];
        off_ws[7 * NPIX + pix] = a7 + bl[7];
        off_ws[8 * NPIX + pix] = a8 + bl[8];
    } else {
        off_ws[ 9 * NPIX + pix] = a9  + bl[9];
        off_ws[10 * NPIX + pix] = a10 + bl[10];
        off_ws[11 * NPIX + pix] = a11 + bl[11];
        off_ws[12 * NPIX + pix] = a12 + bl[12];
        off_ws[13 * NPIX + pix] = a13 + bl[13];
        off_ws[14 * NPIX + pix] = a14 + bl[14];
        off_ws[15 * NPIX + pix] = a15 + bl[15];
        off_ws[16 * NPIX + pix] = a16 + bl[16];
        off_ws[17 * NPIX + pix] = a17 + bl[17];
    }
}

// ------ Kernel B: bilinear deformable sampling + 32-ch matmul + ReLU --------
// block = 256 threads = 128 pixels x 2 channel-halves (sub = lane>>5).
__global__ __launch_bounds__(256, 4) void dcn_sample(
    const float* __restrict__ xT,      // (8, 160, 160, 32)
    const float* __restrict__ w_dcn,   // (32, 32, 3, 3)
    const float* __restrict__ off_ws,  // [18][NPIX]
    float* __restrict__ out)           // (8, 32, 160, 160)
{
    __shared__ __align__(16) float wl[9 * 32 * 32];  // [tap][c][o]
    const int tid = threadIdx.x;
    for (int d = tid; d < 9 * 1024; d += 256) {
        int tap = d >> 10, c = (d >> 5) & 31, o = d & 31;
        wl[d] = w_dcn[(o * 32 + c) * 9 + tap];
    }
    __syncthreads();

    const int lane = tid & 63;
    const int sub = lane >> 5;                      // 0..1 -> channels sub*16..
    const int pl = (tid >> 6) * 32 + (lane & 31);   // 0..127
    const int pix = blockIdx.x * 128 + pl;
    const int w = pix % W_;
    const int h = (pix / W_) % H_;
    const int b = pix / HW_;
    const float* __restrict__ xb = xT + (size_t)b * HW_ * CIN + sub * 16;

    float s0 = 0, s1 = 0, s2 = 0, s3 = 0, s4 = 0, s5 = 0, s6 = 0, s7 = 0;
    float s8 = 0, s9 = 0, s10 = 0, s11 = 0, s12 = 0, s13 = 0, s14 = 0, s15 = 0;
    float s16 = 0, s17 = 0, s18 = 0, s19 = 0, s20 = 0, s21 = 0, s22 = 0, s23 = 0;
    float s24 = 0, s25 = 0, s26 = 0, s27 = 0, s28 = 0, s29 = 0, s30 = 0, s31 = 0;

    #define FMA32(v, wptr) { \
        float4 q; \
        q = ((const float4*)(wptr))[0]; \
        s0 = fmaf((v), q.x, s0);   s1 = fmaf((v), q.y, s1); \
        s2 = fmaf((v), q.z, s2);   s3 = fmaf((v), q.w, s3); \
        q = ((const float4*)(wptr))[1]; \
        s4 = fmaf((v), q.x, s4);   s5 = fmaf((v), q.y, s5); \
        s6 = fmaf((v), q.z, s6);   s7 = fmaf((v), q.w, s7); \
        q = ((const float4*)(wptr))[2]; \
        s8 = fmaf((v), q.x, s8);   s9 = fmaf((v), q.y, s9); \
        s10 = fmaf((v), q.z, s10); s11 = fmaf((v), q.w, s11); \
        q = ((const float4*)(wptr))[3]; \
        s12 = fmaf((v), q.x, s12); s13 = fmaf((v), q.y, s13); \
        s14 = fmaf((v), q.z, s14); s15 = fmaf((v), q.w, s15); \
        q = ((const float4*)(wptr))[4]; \
        s16 = fmaf((v), q.x, s16); s17 = fmaf((v), q.y, s17); \
        s18 = fmaf((v), q.z, s18); s19 = fmaf((v), q.w, s19); \
        q = ((const float4*)(wptr))[5]; \
        s20 = fmaf((v), q.x, s20); s21 = fmaf((v), q.y, s21); \
        s22 = fmaf((v), q.z, s22); s23 = fmaf((v), q.w, s23); \
        q = ((const float4*)(wptr))[6]; \
        s24 = fmaf((v), q.x, s24); s25 = fmaf((v), q.y, s25); \
        s26 = fmaf((v), q.z, s26); s27 = fmaf((v), q.w, s27); \
        q = ((const float4*)(wptr))[7]; \
        s28 = fmaf((v), q.x, s28); s29 = fmaf((v), q.y, s29); \
        s30 = fmaf((v), q.z, s30); s31 = fmaf((v), q.w, s31); }

    #pragma unroll 1
    for (int tap = 0; tap < 9; ++tap) {
        const float dy = off_ws[(2 * tap) * NPIX + pix];
        const float dx = off_ws[(2 * tap + 1) * NPIX + pix];
        const float py = (float)(h - 1 + tap / 3) + dy;
        const float px = (float)(w - 1 + tap % 3) + dx;
        const float fy0 = floorf(py), fx0 = floorf(px);
        const float wy1 = py - fy0, wx1 = px - fx0;
        const float wy0 = 1.0f - wy1, wx0 = 1.0f - wx1;
        const int y0 = (int)fy0, x0 = (int)fx0;
        const int y1 = y0 + 1, x1 = x0 + 1;
        const bool vy0 = (y0 >= 0) && (y0 < H_);
        const bool vy1 = (y1 >= 0) && (y1 < H_);
        const bool vx0 = (x0 >= 0) && (x0 < W_);
        const bool vx1 = (x1 >= 0) && (x1 < W_);
        const float w00 = (vy0 && vx0) ? wy0 * wx0 : 0.0f;
        const float w01 = (vy0 && vx1) ? wy0 * wx1 : 0.0f;
        const float w10 = (vy1 && vx0) ? wy1 * wx0 : 0.0f;
        const float w11 = (vy1 && vx1) ? wy1 * wx1 : 0.0f;
        const int yc0 = min(max(y0, 0), H_ - 1), yc1 = min(max(y1, 0), H_ - 1);
        const int xc0 = min(max(x0, 0), W_ - 1), xc1 = min(max(x1, 0), W_ - 1);
        const float* __restrict__ pA = xb + (size_t)(yc0 * W_ + xc0) * CIN;
        const float* __restrict__ pB = xb + (size_t)(yc0 * W_ + xc1) * CIN;
        const float* __restrict__ pC = xb + (size_t)(yc1 * W_ + xc0) * CIN;
        const float* __restrict__ pD = xb + (size_t)(yc1 * W_ + xc1) * CIN;

        #pragma unroll
        for (int hh = 0; hh < 2; ++hh) {
            const int co = hh * 8;
            // 8 independent float4 gathers (one vaddr per corner + imm offsets)
            const float4 A0 = ((const float4*)(pA + co))[0];
            const float4 A1 = ((const float4*)(pA + co))[1];
            const float4 B0 = ((const float4*)(pB + co))[0];
            const float4 B1 = ((const float4*)(pB + co))[1];
            const float4 C0 = ((const float4*)(pC + co))[0];
            const float4 C1 = ((const float4*)(pC + co))[1];
            const float4 D0 = ((const float4*)(pD + co))[0];
            const float4 D1 = ((const float4*)(pD + co))[1];
            float4 v0, v1;
            v0.x = fmaf(w00, A0.x, fmaf(w01, B0.x, fmaf(w10, C0.x, w11 * D0.x)));
            v0.y = fmaf(w00, A0.y, fmaf(w01, B0.y, fmaf(w10, C0.y, w11 * D0.y)));
            v0.z = fmaf(w00, A0.z, fmaf(w01, B0.z, fmaf(w10, C0.z, w11 * D0.z)));
            v0.w = fmaf(w00, A0.w, fmaf(w01, B0.w, fmaf(w10, C0.w, w11 * D0.w)));
            v1.x = fmaf(w00, A1.x, fmaf(w01, B1.x, fmaf(w10, C1.x, w11 * D1.x)));
            v1.y = fmaf(w00, A1.y, fmaf(w01, B1.y, fmaf(w10, C1.y, w11 * D1.y)));
            v1.z = fmaf(w00, A1.z, fmaf(w01, B1.z, fmaf(w10, C1.z, w11 * D1.z)));
            v1.w = fmaf(w00, A1.w, fmaf(w01, B1.w, fmaf(w10, C1.w, w11 * D1.w)));
            const float* __restrict__ wt = &wl[tap * 1024 + (sub * 16 + co) * 32];
            FMA32(v0.x, wt + 0);
            FMA32(v0.y, wt + 32);
            FMA32(v0.z, wt + 64);
            FMA32(v0.w, wt + 96);
            FMA32(v1.x, wt + 128);
            FMA32(v1.y, wt + 160);
            FMA32(v1.z, wt + 192);
            FMA32(v1.w, wt + 224);
        }
    }
    #undef FMA32

    #define RED(v) v += __shfl_xor(v, 32)
    RED(s0);  RED(s1);  RED(s2);  RED(s3);  RED(s4);  RED(s5);  RED(s6);  RED(s7);
    RED(s8);  RED(s9);  RED(s10); RED(s11); RED(s12); RED(s13); RED(s14); RED(s15);
    RED(s16); RED(s17); RED(s18); RED(s19); RED(s20); RED(s21); RED(s22); RED(s23);
    RED(s24); RED(s25); RED(s26); RED(s27); RED(s28); RED(s29); RED(s30); RED(s31);
    #undef RED

    float* __restrict__ ob = out + (size_t)b * COUT * HW_ + h * W_ + w;
    if (sub == 0) {
        ob[ 0 * HW_] = fmaxf(s0, 0.0f);   ob[ 1 * HW_] = fmaxf(s1, 0.0f);
        ob[ 2 * HW_] = fmaxf(s2, 0.0f);   ob[ 3 * HW_] = fmaxf(s3, 0.0f);
        ob[ 4 * HW_] = fmaxf(s4, 0.0f);   ob[ 5 * HW_] = fmaxf(s5, 0.0f);
        ob[ 6 * HW_] = fmaxf(s6, 0.0f);   ob[ 7 * HW_] = fmaxf(s7, 0.0f);
        ob[ 8 * HW_] = fmaxf(s8, 0.0f);   ob[ 9 * HW_] = fmaxf(s9, 0.0f);
        ob[10 * HW_] = fmaxf(s10, 0.0f);  ob[11 * HW_] = fmaxf(s11, 0.0f);
        ob[12 * HW_] = fmaxf(s12, 0.0f);  ob[13 * HW_] = fmaxf(s13, 0.0f);
        ob[14 * HW_] = fmaxf(s14, 0.0f);  ob[15 * HW_] = fmaxf(s15, 0.0f);
    } else {
        ob[16 * HW_] = fmaxf(s16, 0.0f);  ob[17 * HW_] = fmaxf(s17, 0.0f);
        ob[18 * HW_] = fmaxf(s18, 0.0f);  ob[19 * HW_] = fmaxf(s19, 0.0f);
        ob[20 * HW_] = fmaxf(s20, 0.0f);  ob[21 * HW_] = fmaxf(s21, 0.0f);
        ob[22 * HW_] = fmaxf(s22, 0.0f);  ob[23 * HW_] = fmaxf(s23, 0.0f);
        ob[24 * HW_] = fmaxf(s24, 0.0f);  ob[25 * HW_] = fmaxf(s25, 0.0f);
        ob[26 * HW_] = fmaxf(s26, 0.0f);  ob[27 * HW_] = fmaxf(s27, 0.0f);
        ob[28 * HW_] = fmaxf(s28, 0.0f);  ob[29 * HW_] = fmaxf(s29, 0.0f);
        ob[30 * HW_] = fmaxf(s30, 0.0f);  ob[31 * HW_] = fmaxf(s31, 0.0f);
    }
}

extern "C" void kernel_launch(void* const* d_in, const int* in_sizes, int n_in,
                              void* d_out, int out_size, void* d_ws, size_t ws_size,
                              hipStream_t stream) {
    const float* x     = (const float*)d_in[0];
    const float* w_off = (const float*)d_in[1];
    const float* b_off = (const float*)d_in[2];
    const float* w_dcn = (const float*)d_in[3];
    float* out    = (float*)d_out;
    float* xT     = (float*)d_ws;                   // 26.2 MB (NPIX*32 floats)
    float* off_ws = (float*)d_ws + (size_t)NPIX * CIN;  // +14.75 MB

    nhwc_transpose<<<800, 256, 0, stream>>>(x, xT);
    dcn_offset<<<1600, 256, 0, stream>>>(xT, w_off, b_off, off_ws);
    dcn_sample<<<1600, 256, 0, stream>>>(xT, w_dcn, off_ws, out);
}

// Round 7
// 180.180 us; speedup vs baseline: 1.9912x; 1.9912x over previous
//
#include <hip/hip_runtime.h>

#define H_ 160
#define W_ 160
#define HW_ (H_ * W_)
#define NPIX (8 * HW_)   // 204800 pixels

// ============================================================================
// R7: MFMA rewrite. R3-R6 were LDS-pipe-bound: per-pixel VALU weight multiply
// re-broadcast 128B of weights from LDS per sampled value (~346K LDS cyc/CU
// = 144us floor). MFMA reads weights as B-fragments: 2 ds_read_b128 per
// wave-tap serving 16 pixels x 32 outputs. A-fragments built in registers
// from NHWC-bf16 gathers (lane = (pixel m = lane&15, k-chunk q = lane>>4),
// 8 contiguous channels = one 16B load). Layouts per verified m89/m91:
//   A[m=lane&15][k=q*8+j], B[n=lane&15][k=q*8+j], D: col n=lane&15,
//   row m = q*4+reg.
// ============================================================================

typedef __attribute__((ext_vector_type(8))) short short8;   // 8 bf16
typedef __attribute__((ext_vector_type(4))) float f32x4;
typedef __attribute__((ext_vector_type(4))) unsigned u32x4;

__device__ __forceinline__ unsigned short bf16_rne(float f) {
    unsigned u = __float_as_uint(f);
    u += 0x7fffu + ((u >> 16) & 1u);
    return (unsigned short)(u >> 16);
}
__device__ __forceinline__ unsigned pack2_bf16(float a, float b) {
    unsigned ua = __float_as_uint(a); ua += 0x7fffu + ((ua >> 16) & 1u);
    unsigned ub = __float_as_uint(b); ub += 0x7fffu + ((ub >> 16) & 1u);
    return (ua >> 16) | (ub & 0xffff0000u);
}
__device__ __forceinline__ float blo(unsigned u) { return __uint_as_float(u << 16); }
__device__ __forceinline__ float bhi(unsigned u) { return __uint_as_float(u & 0xffff0000u); }

// ---- x (B,32,H,W) fp32 -> xT (B,H,W,32) bf16 -------------------------------
__global__ __launch_bounds__(256) void nhwc_bf16(
    const float* __restrict__ x, unsigned short* __restrict__ xT)
{
    const int pix = blockIdx.x * 256 + threadIdx.x;
    const int p = pix % HW_;
    const int b = pix / HW_;
    const float* __restrict__ src = x + (size_t)b * 32 * HW_ + p;
    unsigned* __restrict__ dst = (unsigned*)(xT + (size_t)pix * 32);
    #pragma unroll
    for (int g = 0; g < 16; ++g)
        dst[g] = pack2_bf16(src[(2 * g) * HW_], src[(2 * g + 1) * HW_]);
}

// ---- Kernel A: offset conv as MFMA GEMM (N=18 padded to 32) ----------------
__global__ __launch_bounds__(256) void dcn_offset_mfma(
    const unsigned short* __restrict__ xT,
    const float* __restrict__ w_off,    // (18, 32, 3, 3)
    const float* __restrict__ b_off,    // (18,)
    float* __restrict__ off_ws)         // [18][NPIX] fp32
{
    __shared__ unsigned short wl[9 * 32 * 40];  // [tap][j(32,pad-zero>=18)][c], row pad 40
    __shared__ float bl[32];
    const int tid = threadIdx.x;
    for (int d = tid; d < 9 * 32 * 32; d += 256) {
        const int tap = d >> 10, j = (d >> 5) & 31, c = d & 31;
        wl[tap * 1280 + j * 40 + c] =
            (j < 18) ? bf16_rne(w_off[(j * 32 + c) * 9 + tap]) : (unsigned short)0;
    }
    if (tid < 32) bl[tid] = (tid < 18) ? b_off[tid] : 0.0f;
    __syncthreads();

    const int wave = tid >> 6, lane = tid & 63;
    const int mrow = lane & 15, q = lane >> 4;
    const int mbase = blockIdx.x * 64 + wave * 16;   // 16 pixels per wave
    const int pix = mbase + mrow;
    const int w = pix % W_, h = (pix / W_) % H_, b = pix / HW_;
    const unsigned short* __restrict__ xb = xT + (size_t)b * HW_ * 32 + q * 8;

    f32x4 acc0 = {0.f, 0.f, 0.f, 0.f};
    f32x4 acc1 = {0.f, 0.f, 0.f, 0.f};

    #pragma unroll
    for (int tap = 0; tap < 9; ++tap) {
        const int yy = h - 1 + tap / 3;
        const int xx = w - 1 + tap % 3;
        const bool valid = (yy >= 0) && (yy < H_) && (xx >= 0) && (xx < W_);
        const int idx = min(max(yy, 0), H_ - 1) * W_ + min(max(xx, 0), W_ - 1);
        const u32x4 za = {0u, 0u, 0u, 0u};
        u32x4 ua = *(const u32x4*)(xb + (size_t)idx * 32);
        ua = valid ? ua : za;
        const short8 afrag = __builtin_bit_cast(short8, ua);
        const unsigned short* wt = &wl[tap * 1280 + q * 8];
        const short8 b0 = *(const short8*)(wt + mrow * 40);
        const short8 b1 = *(const short8*)(wt + (16 + mrow) * 40);
        acc0 = __builtin_amdgcn_mfma_f32_16x16x32_bf16(afrag, b0, acc0, 0, 0, 0);
        acc1 = __builtin_amdgcn_mfma_f32_16x16x32_bf16(afrag, b1, acc1, 0, 0, 0);
    }

    // D: col j = lane&15 (+16 for acc1), rows m = q*4 + r
    const float bia0 = bl[mrow];
    const float bia1 = bl[16 + mrow];
    #pragma unroll
    for (int r = 0; r < 4; ++r) {
        const int pr = mbase + q * 4 + r;
        off_ws[mrow * NPIX + pr] = acc0[r] + bia0;
        if (mrow < 2) off_ws[(16 + mrow) * NPIX + pr] = acc1[r] + bia1;
    }
}

// ---- Kernel B: bilinear sampling + MFMA GEMM (N=32) + ReLU -----------------
__global__ __launch_bounds__(256) void dcn_sample_mfma(
    const unsigned short* __restrict__ xT,
    const float* __restrict__ w_dcn,    // (32, 32, 3, 3)
    const float* __restrict__ off_ws,   // [18][NPIX]
    float* __restrict__ out)            // (8, 32, 160, 160)
{
    __shared__ unsigned short wl[9 * 32 * 40];  // [tap][o(32)][c(32)], row pad 40
    const int tid = threadIdx.x;
    for (int d = tid; d < 9 * 32 * 32; d += 256) {
        const int tap = d >> 10, o = (d >> 5) & 31, c = d & 31;
        wl[tap * 1280 + o * 40 + c] = bf16_rne(w_dcn[(o * 32 + c) * 9 + tap]);
    }
    __syncthreads();

    const int wave = tid >> 6, lane = tid & 63;
    const int mrow = lane & 15, q = lane >> 4;
    const int mbase = blockIdx.x * 64 + wave * 16;   // 16 pixels per wave
    const int pix = mbase + mrow;
    const int w = pix % W_, h = (pix / W_) % H_, b = pix / HW_;
    const unsigned short* __restrict__ xb = xT + (size_t)b * HW_ * 32 + q * 8;

    f32x4 acc0 = {0.f, 0.f, 0.f, 0.f};
    f32x4 acc1 = {0.f, 0.f, 0.f, 0.f};

    #pragma unroll
    for (int tap = 0; tap < 9; ++tap) {
        const float dy = off_ws[(2 * tap) * NPIX + pix];
        const float dx = off_ws[(2 * tap + 1) * NPIX + pix];
        const float py = (float)(h - 1 + tap / 3) + dy;
        const float px = (float)(w - 1 + tap % 3) + dx;
        const float fy0 = floorf(py), fx0 = floorf(px);
        const float wy1 = py - fy0, wx1 = px - fx0;
        const float wy0 = 1.0f - wy1, wx0 = 1.0f - wx1;
        const int y0 = (int)fy0, x0i = (int)fx0;
        const int y1 = y0 + 1, x1i = x0i + 1;
        const bool vy0 = (y0 >= 0) && (y0 < H_);
        const bool vy1 = (y1 >= 0) && (y1 < H_);
        const bool vx0 = (x0i >= 0) && (x0i < W_);
        const bool vx1 = (x1i >= 0) && (x1i < W_);
        const float w00 = (vy0 && vx0) ? wy0 * wx0 : 0.0f;
        const float w01 = (vy0 && vx1) ? wy0 * wx1 : 0.0f;
        const float w10 = (vy1 && vx0) ? wy1 * wx0 : 0.0f;
        const float w11 = (vy1 && vx1) ? wy1 * wx1 : 0.0f;
        const int yc0 = min(max(y0, 0), H_ - 1), yc1 = min(max(y1, 0), H_ - 1);
        const int xc0 = min(max(x0i, 0), W_ - 1), xc1 = min(max(x1i, 0), W_ - 1);

        // 4 corner loads: 8 contiguous bf16 channels each (16 B, coalesced-ish)
        const u32x4 A = *(const u32x4*)(xb + (size_t)(yc0 * W_ + xc0) * 32);
        const u32x4 B = *(const u32x4*)(xb + (size_t)(yc0 * W_ + xc1) * 32);
        const u32x4 C = *(const u32x4*)(xb + (size_t)(yc1 * W_ + xc0) * 32);
        const u32x4 D = *(const u32x4*)(xb + (size_t)(yc1 * W_ + xc1) * 32);

        u32x4 av;
        {
            const float v0 = w00*blo(A.x) + w01*blo(B.x) + w10*blo(C.x) + w11*blo(D.x);
            const float v1 = w00*bhi(A.x) + w01*bhi(B.x) + w10*bhi(C.x) + w11*bhi(D.x);
            av.x = pack2_bf16(v0, v1);
        }
        {
            const float v0 = w00*blo(A.y) + w01*blo(B.y) + w10*blo(C.y) + w11*blo(D.y);
            const float v1 = w00*bhi(A.y) + w01*bhi(B.y) + w10*bhi(C.y) + w11*bhi(D.y);
            av.y = pack2_bf16(v0, v1);
        }
        {
            const float v0 = w00*blo(A.z) + w01*blo(B.z) + w10*blo(C.z) + w11*blo(D.z);
            const float v1 = w00*bhi(A.z) + w01*bhi(B.z) + w10*bhi(C.z) + w11*bhi(D.z);
            av.z = pack2_bf16(v0, v1);
        }
        {
            const float v0 = w00*blo(A.w) + w01*blo(B.w) + w10*blo(C.w) + w11*blo(D.w);
            const float v1 = w00*bhi(A.w) + w01*bhi(B.w) + w10*bhi(C.w) + w11*bhi(D.w);
            av.w = pack2_bf16(v0, v1);
        }
        const short8 afrag = __builtin_bit_cast(short8, av);

        const unsigned short* wt = &wl[tap * 1280 + q * 8];
        const short8 b0 = *(const short8*)(wt + mrow * 40);
        const short8 b1 = *(const short8*)(wt + (16 + mrow) * 40);
        acc0 = __builtin_amdgcn_mfma_f32_16x16x32_bf16(afrag, b0, acc0, 0, 0, 0);
        acc1 = __builtin_amdgcn_mfma_f32_16x16x32_bf16(afrag, b1, acc1, 0, 0, 0);
    }

    // D: col o = lane&15 (+16 for acc1), rows m = q*4 + r. Whole block is in
    // one image (HW_ % 64 == 0), so b is block-uniform.
    float* __restrict__ ob = out + (size_t)b * 32 * HW_;
    const int pb = mbase - b * HW_ + q * 4;
    #pragma unroll
    for (int r = 0; r < 4; ++r) {
        ob[mrow * HW_ + pb + r]        = fmaxf(acc0[r], 0.0f);
        ob[(16 + mrow) * HW_ + pb + r] = fmaxf(acc1[r], 0.0f);
    }
}

extern "C" void kernel_launch(void* const* d_in, const int* in_sizes, int n_in,
                              void* d_out, int out_size, void* d_ws, size_t ws_size,
                              hipStream_t stream) {
    const float* x     = (const float*)d_in[0];
    const float* w_off = (const float*)d_in[1];
    const float* b_off = (const float*)d_in[2];
    const float* w_dcn = (const float*)d_in[3];
    float* out = (float*)d_out;

    unsigned short* xT = (unsigned short*)d_ws;                  // 13.1 MB bf16 NHWC
    float* off_ws = (float*)((char*)d_ws + (size_t)NPIX * 32 * 2); // +14.75 MB fp32

    nhwc_bf16<<<800, 256, 0, stream>>>(x, xT);
    dcn_offset_mfma<<<3200, 256, 0, stream>>>(xT, w_off, b_off, off_ws);
    dcn_sample_mfma<<<3200, 256, 0, stream>>>(xT, w_dcn, off_ws, out);
}

// Round 8
// 171.668 us; speedup vs baseline: 2.0900x; 1.0496x over previous
//
#include <hip/hip_runtime.h>

#define H_ 160
#define W_ 160
#define HW_ (H_ * W_)
#define NPIX (8 * HW_)   // 204800 pixels

// ============================================================================
// R8: R7 (MFMA) + latency engineering.
//  - B-fragment LDS is lane-linear ([tap][half][lane] 16B units): each lane
//    reads its own contiguous 16B -> zero bank conflicts (R7: 921K conflicts
//    from 40-ushort row stride).
//  - __launch_bounds__(256,4): R7's VGPR=40 starved the scheduler; gathers
//    serialized (VALUBusy 45%, latency-bound). Now: all dy/dx loaded upfront,
//    corner gathers software-pipelined 3 taps ahead of the MFMA consuming them.
//  - float4 stores in both epilogues.
// MFMA layouts per verified m89/m91: A[m=lane&15][k=(lane>>4)*8+j],
// B[n=lane&15][k=...], D: col n=lane&15, row m=(lane>>4)*4+reg.
// ============================================================================

typedef __attribute__((ext_vector_type(8))) short short8;   // 8 bf16
typedef __attribute__((ext_vector_type(4))) float f32x4;
typedef __attribute__((ext_vector_type(4))) unsigned u32x4;

__device__ __forceinline__ unsigned short bf16_rne(float f) {
    unsigned u = __float_as_uint(f);
    u += 0x7fffu + ((u >> 16) & 1u);
    return (unsigned short)(u >> 16);
}
__device__ __forceinline__ unsigned pack2_bf16(float a, float b) {
    unsigned ua = __float_as_uint(a); ua += 0x7fffu + ((ua >> 16) & 1u);
    unsigned ub = __float_as_uint(b); ub += 0x7fffu + ((ub >> 16) & 1u);
    return (ua >> 16) | (ub & 0xffff0000u);
}
__device__ __forceinline__ float blo(unsigned u) { return __uint_as_float(u << 16); }
__device__ __forceinline__ float bhi(unsigned u) { return __uint_as_float(u & 0xffff0000u); }

// ---- x (B,32,H,W) fp32 -> xT (B,H,W,32) bf16 -------------------------------
__global__ __launch_bounds__(256) void nhwc_bf16(
    const float* __restrict__ x, unsigned short* __restrict__ xT)
{
    const int pix = blockIdx.x * 256 + threadIdx.x;
    const int p = pix % HW_;
    const int b = pix / HW_;
    const float* __restrict__ src = x + (size_t)b * 32 * HW_ + p;
    unsigned* __restrict__ dst = (unsigned*)(xT + (size_t)pix * 32);
    #pragma unroll
    for (int g = 0; g < 16; ++g)
        dst[g] = pack2_bf16(src[(2 * g) * HW_], src[(2 * g + 1) * HW_]);
}

// ---- Kernel A: offset conv as MFMA GEMM (N=18 padded to 32) ----------------
__global__ __launch_bounds__(256, 4) void dcn_offset_mfma(
    const unsigned short* __restrict__ xT,
    const float* __restrict__ w_off,    // (18, 32, 3, 3)
    const float* __restrict__ b_off,    // (18,)
    float* __restrict__ off_ws)         // [18][NPIX] fp32
{
    // lane-linear B-fragments: 16B unit index = tap*128 + half*64 + lane
    __shared__ __align__(16) unsigned short wl[9 * 128 * 8];
    __shared__ float bl[32];
    const int tid = threadIdx.x;
    for (int d = tid; d < 9 * 1024; d += 256) {
        const int tap = d >> 10, j = (d >> 5) & 31, c = d & 31;
        const int unit = tap * 128 + (j >> 4) * 64 + ((c >> 3) << 4) + (j & 15);
        wl[unit * 8 + (c & 7)] =
            (j < 18) ? bf16_rne(w_off[(j * 32 + c) * 9 + tap]) : (unsigned short)0;
    }
    if (tid < 32) bl[tid] = (tid < 18) ? b_off[tid] : 0.0f;

    const int wave = tid >> 6, lane = tid & 63;
    const int mrow = lane & 15, q = lane >> 4;
    const int mbase = blockIdx.x * 64 + wave * 16;
    const int pix = mbase + mrow;
    const int w = pix % W_, h = (pix / W_) % H_, b = pix / HW_;
    const unsigned short* __restrict__ xb = xT + (size_t)b * HW_ * 32 + q * 8;

    // all 9 tap loads issued before the barrier (overlap LDS fill + gathers)
    #define OLOAD(t) \
        const int yy_##t = h - 1 + (t) / 3, xx_##t = w - 1 + (t) % 3; \
        const bool val_##t = (yy_##t >= 0) && (yy_##t < H_) && \
                             (xx_##t >= 0) && (xx_##t < W_); \
        const int idx_##t = min(max(yy_##t, 0), H_ - 1) * W_ + \
                            min(max(xx_##t, 0), W_ - 1); \
        const u32x4 ua_##t = *(const u32x4*)(xb + (size_t)idx_##t * 32);
    OLOAD(0) OLOAD(1) OLOAD(2) OLOAD(3) OLOAD(4)
    OLOAD(5) OLOAD(6) OLOAD(7) OLOAD(8)
    #undef OLOAD

    __syncthreads();

    f32x4 acc0 = {0.f, 0.f, 0.f, 0.f};
    f32x4 acc1 = {0.f, 0.f, 0.f, 0.f};
    const u32x4 z4 = {0u, 0u, 0u, 0u};

    #define OCONS(t) { \
        const u32x4 uu = val_##t ? ua_##t : z4; \
        const short8 af = __builtin_bit_cast(short8, uu); \
        const short8 b0 = *(const short8*)(wl + ((t) * 128 + lane) * 8); \
        const short8 b1 = *(const short8*)(wl + ((t) * 128 + 64 + lane) * 8); \
        acc0 = __builtin_amdgcn_mfma_f32_16x16x32_bf16(af, b0, acc0, 0, 0, 0); \
        acc1 = __builtin_amdgcn_mfma_f32_16x16x32_bf16(af, b1, acc1, 0, 0, 0); }
    OCONS(0) OCONS(1) OCONS(2) OCONS(3) OCONS(4)
    OCONS(5) OCONS(6) OCONS(7) OCONS(8)
    #undef OCONS

    const float bia0 = bl[mrow];
    f32x4 r0;
    #pragma unroll
    for (int r = 0; r < 4; ++r) r0[r] = acc0[r] + bia0;
    *(f32x4*)(off_ws + (size_t)mrow * NPIX + mbase + q * 4) = r0;
    if (mrow < 2) {
        const float bia1 = bl[16 + mrow];
        f32x4 r1;
        #pragma unroll
        for (int r = 0; r < 4; ++r) r1[r] = acc1[r] + bia1;
        *(f32x4*)(off_ws + (size_t)(16 + mrow) * NPIX + mbase + q * 4) = r1;
    }
}

// ---- Kernel B: bilinear sampling + MFMA GEMM (N=32) + ReLU -----------------
__global__ __launch_bounds__(256, 4) void dcn_sample_mfma(
    const unsigned short* __restrict__ xT,
    const float* __restrict__ w_dcn,    // (32, 32, 3, 3)
    const float* __restrict__ off_ws,   // [18][NPIX]
    float* __restrict__ out)            // (8, 32, 160, 160)
{
    __shared__ __align__(16) unsigned short wl[9 * 128 * 8];
    const int tid = threadIdx.x;
    for (int d = tid; d < 9 * 1024; d += 256) {
        const int tap = d >> 10, o = (d >> 5) & 31, c = d & 31;
        const int unit = tap * 128 + (o >> 4) * 64 + ((c >> 3) << 4) + (o & 15);
        wl[unit * 8 + (c & 7)] = bf16_rne(w_dcn[(o * 32 + c) * 9 + tap]);
    }

    const int wave = tid >> 6, lane = tid & 63;
    const int mrow = lane & 15, q = lane >> 4;
    const int mbase = blockIdx.x * 64 + wave * 16;
    const int pix = mbase + mrow;
    const int w = pix % W_, h = (pix / W_) % H_, b = pix / HW_;
    const unsigned short* __restrict__ xb = xT + (size_t)b * HW_ * 32 + q * 8;

    // all 18 offset loads issued before the barrier
    #define DLOAD(t) \
        const float dy_##t = off_ws[(2 * (t)) * NPIX + pix]; \
        const float dx_##t = off_ws[(2 * (t) + 1) * NPIX + pix];
    DLOAD(0) DLOAD(1) DLOAD(2) DLOAD(3) DLOAD(4)
    DLOAD(5) DLOAD(6) DLOAD(7) DLOAD(8)
    #undef DLOAD

    __syncthreads();

    f32x4 acc0 = {0.f, 0.f, 0.f, 0.f};
    f32x4 acc1 = {0.f, 0.f, 0.f, 0.f};

    // PREP: bilinear weights + issue 4 corner gathers for tap t
    #define PREP(t) \
        const float py_##t = (float)(h - 1 + (t) / 3) + dy_##t; \
        const float px_##t = (float)(w - 1 + (t) % 3) + dx_##t; \
        const float fy_##t = floorf(py_##t), fx_##t = floorf(px_##t); \
        const float wy1_##t = py_##t - fy_##t, wx1_##t = px_##t - fx_##t; \
        const float wy0_##t = 1.0f - wy1_##t, wx0_##t = 1.0f - wx1_##t; \
        const int y0_##t = (int)fy_##t, x0_##t = (int)fx_##t; \
        const bool vy0_##t = (y0_##t >= 0) && (y0_##t < H_); \
        const bool vy1_##t = (y0_##t + 1 >= 0) && (y0_##t + 1 < H_); \
        const bool vx0_##t = (x0_##t >= 0) && (x0_##t < W_); \
        const bool vx1_##t = (x0_##t + 1 >= 0) && (x0_##t + 1 < W_); \
        const float w00_##t = (vy0_##t && vx0_##t) ? wy0_##t * wx0_##t : 0.0f; \
        const float w01_##t = (vy0_##t && vx1_##t) ? wy0_##t * wx1_##t : 0.0f; \
        const float w10_##t = (vy1_##t && vx0_##t) ? wy1_##t * wx0_##t : 0.0f; \
        const float w11_##t = (vy1_##t && vx1_##t) ? wy1_##t * wx1_##t : 0.0f; \
        const int yc0_##t = min(max(y0_##t, 0), H_ - 1); \
        const int yc1_##t = min(max(y0_##t + 1, 0), H_ - 1); \
        const int xc0_##t = min(max(x0_##t, 0), W_ - 1); \
        const int xc1_##t = min(max(x0_##t + 1, 0), W_ - 1); \
        const u32x4 A_##t = *(const u32x4*)(xb + (size_t)(yc0_##t * W_ + xc0_##t) * 32); \
        const u32x4 B_##t = *(const u32x4*)(xb + (size_t)(yc0_##t * W_ + xc1_##t) * 32); \
        const u32x4 C_##t = *(const u32x4*)(xb + (size_t)(yc1_##t * W_ + xc0_##t) * 32); \
        const u32x4 D_##t = *(const u32x4*)(xb + (size_t)(yc1_##t * W_ + xc1_##t) * 32);

    // CONS: bilinear combine -> bf16 A-fragment -> 2x MFMA
    #define CONS(t) { \
        u32x4 av; \
        { const float v0 = w00_##t*blo(A_##t.x) + w01_##t*blo(B_##t.x) \
                         + w10_##t*blo(C_##t.x) + w11_##t*blo(D_##t.x); \
          const float v1 = w00_##t*bhi(A_##t.x) + w01_##t*bhi(B_##t.x) \
                         + w10_##t*bhi(C_##t.x) + w11_##t*bhi(D_##t.x); \
          av.x = pack2_bf16(v0, v1); } \
        { const float v0 = w00_##t*blo(A_##t.y) + w01_##t*blo(B_##t.y) \
                         + w10_##t*blo(C_##t.y) + w11_##t*blo(D_##t.y); \
          const float v1 = w00_##t*bhi(A_##t.y) + w01_##t*bhi(B_##t.y) \
                         + w10_##t*bhi(C_##t.y) + w11_##t*bhi(D_##t.y); \
          av.y = pack2_bf16(v0, v1); } \
        { const float v0 = w00_##t*blo(A_##t.z) + w01_##t*blo(B_##t.z) \
                         + w10_##t*blo(C_##t.z) + w11_##t*blo(D_##t.z); \
          const float v1 = w00_##t*bhi(A_##t.z) + w01_##t*bhi(B_##t.z) \
                         + w10_##t*bhi(C_##t.z) + w11_##t*bhi(D_##t.z); \
          av.z = pack2_bf16(v0, v1); } \
        { const float v0 = w00_##t*blo(A_##t.w) + w01_##t*blo(B_##t.w) \
                         + w10_##t*blo(C_##t.w) + w11_##t*blo(D_##t.w); \
          const float v1 = w00_##t*bhi(A_##t.w) + w01_##t*bhi(B_##t.w) \
                         + w10_##t*bhi(C_##t.w) + w11_##t*bhi(D_##t.w); \
          av.w = pack2_bf16(v0, v1); } \
        const short8 af = __builtin_bit_cast(short8, av); \
        const short8 b0 = *(const short8*)(wl + ((t) * 128 + lane) * 8); \
        const short8 b1 = *(const short8*)(wl + ((t) * 128 + 64 + lane) * 8); \
        acc0 = __builtin_amdgcn_mfma_f32_16x16x32_bf16(af, b0, acc0, 0, 0, 0); \
        acc1 = __builtin_amdgcn_mfma_f32_16x16x32_bf16(af, b1, acc1, 0, 0, 0); }

    // 3-deep pipeline: gathers in flight 2-3 taps ahead of their MFMA
    PREP(0) PREP(1) PREP(2)
    CONS(0) PREP(3)
    CONS(1) PREP(4)
    CONS(2) PREP(5)
    CONS(3) PREP(6)
    CONS(4) PREP(7)
    CONS(5) PREP(8)
    CONS(6) CONS(7) CONS(8)
    #undef PREP
    #undef CONS

    float* __restrict__ ob = out + (size_t)b * 32 * HW_;
    const int pb = mbase - b * HW_ + q * 4;
    f32x4 r0, r1;
    #pragma unroll
    for (int r = 0; r < 4; ++r) {
        r0[r] = fmaxf(acc0[r], 0.0f);
        r1[r] = fmaxf(acc1[r], 0.0f);
    }
    *(f32x4*)(ob + (size_t)mrow * HW_ + pb) = r0;
    *(f32x4*)(ob + (size_t)(16 + mrow) * HW_ + pb) = r1;
}

extern "C" void kernel_launch(void* const* d_in, const int* in_sizes, int n_in,
                              void* d_out, int out_size, void* d_ws, size_t ws_size,
                              hipStream_t stream) {
    const float* x     = (const float*)d_in[0];
    const float* w_off = (const float*)d_in[1];
    const float* b_off = (const float*)d_in[2];
    const float* w_dcn = (const float*)d_in[3];
    float* out = (float*)d_out;

    unsigned short* xT = (unsigned short*)d_ws;                    // 13.1 MB bf16 NHWC
    float* off_ws = (float*)((char*)d_ws + (size_t)NPIX * 32 * 2); // +14.75 MB fp32

    nhwc_bf16<<<800, 256, 0, stream>>>(x, xT);
    dcn_offset_mfma<<<3200, 256, 0, stream>>>(xT, w_off, b_off, off_ws);
    dcn_sample_mfma<<<3200, 256, 0, stream>>>(xT, w_dcn, off_ws, out);
}

// Round 9
// 159.676 us; speedup vs baseline: 2.2469x; 1.0751x over previous
//
#include <hip/hip_runtime.h>

#define H_ 160
#define W_ 160
#define HW_ (H_ * W_)
#define NPIX (8 * HW_)   // 204800 pixels

// ============================================================================
// R9: 32x32x16 MFMA (32 pixels/wave). R7/R8 at 67us were VALU-issue-bound:
// ~2900 wave-instrs per 16 pixels (bilinear PREP + unpack/pack dominate).
// 32x32 tile amortizes all wave-wide scalar work over 2x pixels; f32x2
// packed math (v_pk_fma_f32) halves the combine. B-frags lane-linear in LDS.
// Layouts (verified m74/m101): A[m=lane&31][k=(lane>>5)*8+j],
// B[n=lane&31][k=...], D: col n=lane&31, row=(reg&3)+8*(reg>>2)+4*(lane>>5).
// ============================================================================

typedef __attribute__((ext_vector_type(8)))  short  short8;   // 8 bf16
typedef __attribute__((ext_vector_type(4)))  float  f32x4;
typedef __attribute__((ext_vector_type(2)))  float  f32x2;
typedef __attribute__((ext_vector_type(16))) float  f32x16;
typedef __attribute__((ext_vector_type(4)))  unsigned u32x4;

__device__ __forceinline__ unsigned short bf16_rne(float f) {
    unsigned u = __float_as_uint(f);
    u += 0x7fffu + ((u >> 16) & 1u);
    return (unsigned short)(u >> 16);
}
__device__ __forceinline__ unsigned pack2_bf16(float a, float b) {
    unsigned ua = __float_as_uint(a); ua += 0x7fffu + ((ua >> 16) & 1u);
    unsigned ub = __float_as_uint(b); ub += 0x7fffu + ((ub >> 16) & 1u);
    return (ua >> 16) | (ub & 0xffff0000u);
}
// bf16 pair -> f32x2 (2 VALU ops; math on f32x2 -> v_pk_fma_f32)
__device__ __forceinline__ f32x2 up2(unsigned u) {
    f32x2 r;
    r.x = __uint_as_float(u << 16);
    r.y = __uint_as_float(u & 0xffff0000u);
    return r;
}

// ---- x (B,32,H,W) fp32 -> xT (B,H,W,32) bf16 -------------------------------
__global__ __launch_bounds__(256) void nhwc_bf16(
    const float* __restrict__ x, unsigned short* __restrict__ xT)
{
    const int pix = blockIdx.x * 256 + threadIdx.x;
    const int p = pix % HW_;
    const int b = pix / HW_;
    const float* __restrict__ src = x + (size_t)b * 32 * HW_ + p;
    unsigned* __restrict__ dst = (unsigned*)(xT + (size_t)pix * 32);
    #pragma unroll
    for (int g = 0; g < 16; ++g)
        dst[g] = pack2_bf16(src[(2 * g) * HW_], src[(2 * g + 1) * HW_]);
}

// ---- Kernel A: offset conv as 32x32 MFMA GEMM (N=18 padded to 32) ----------
__global__ __launch_bounds__(256, 4) void dcn_offset_mfma(
    const unsigned short* __restrict__ xT,
    const float* __restrict__ w_off,    // (18, 32, 3, 3)
    const float* __restrict__ b_off,    // (18,)
    float* __restrict__ off_ws)         // [18][NPIX] fp32
{
    // lane-linear B-frags: unit = (tap*2 + kstep)*64 + lane, 8 bf16 each
    __shared__ __align__(16) unsigned short wl[9 * 2 * 64 * 8];
    __shared__ float bl[32];
    const int tid = threadIdx.x;
    for (int d = tid; d < 9 * 1024; d += 256) {
        const int tap = d >> 10, r = d & 1023, j = r >> 5, c = r & 31;
        const int s = c >> 4, kg = (c >> 3) & 1;
        const int unit = (tap * 2 + s) * 64 + j + 32 * kg;
        wl[unit * 8 + (c & 7)] =
            (j < 18) ? bf16_rne(w_off[(j * 32 + c) * 9 + tap]) : (unsigned short)0;
    }
    if (tid < 32) bl[tid] = (tid < 18) ? b_off[tid] : 0.0f;
    __syncthreads();

    const int wave = tid >> 6, lane = tid & 63;
    const int n = lane & 31;          // A-row m == B-col n == lane&31
    const int hh = lane >> 5;         // k-group
    const int pixbase = blockIdx.x * 128 + wave * 32;
    const int pix = pixbase + n;
    const int w = pix % W_, h = (pix / W_) % H_, b = pix / HW_;
    const unsigned short* __restrict__ xb = xT + (size_t)b * HW_ * 32 + hh * 8;

    f32x16 acc = {};
    const u32x4 z4 = {0u, 0u, 0u, 0u};

    #pragma unroll
    for (int tap = 0; tap < 9; ++tap) {
        const int yy = h - 1 + tap / 3;
        const int xx = w - 1 + tap % 3;
        const bool valid = (yy >= 0) && (yy < H_) && (xx >= 0) && (xx < W_);
        const int idx = min(max(yy, 0), H_ - 1) * W_ + min(max(xx, 0), W_ - 1);
        const unsigned short* __restrict__ p = xb + (size_t)idx * 32;
        u32x4 l0 = *(const u32x4*)(p);        // channels hh*8 .. +7
        u32x4 l1 = *(const u32x4*)(p + 16);   // channels 16+hh*8 .. +7
        l0 = valid ? l0 : z4;
        l1 = valid ? l1 : z4;
        const short8 a0 = __builtin_bit_cast(short8, l0);
        const short8 a1 = __builtin_bit_cast(short8, l1);
        const short8 b0 = *(const short8*)(wl + ((tap * 2 + 0) * 64 + lane) * 8);
        const short8 b1 = *(const short8*)(wl + ((tap * 2 + 1) * 64 + lane) * 8);
        acc = __builtin_amdgcn_mfma_f32_32x32x16_bf16(a0, b0, acc, 0, 0, 0);
        acc = __builtin_amdgcn_mfma_f32_32x32x16_bf16(a1, b1, acc, 0, 0, 0);
    }

    if (n < 18) {
        const float bia = bl[n];
        float* __restrict__ op = off_ws + (size_t)n * NPIX + pixbase + 4 * hh;
        #pragma unroll
        for (int g = 0; g < 4; ++g) {
            f32x4 r;
            #pragma unroll
            for (int i = 0; i < 4; ++i) r[i] = acc[g * 4 + i] + bia;
            *(f32x4*)(op + g * 8) = r;   // rows g*8 + 4*hh + {0..3}
        }
    }
}

// ---- Kernel B: bilinear sampling + 32x32 MFMA GEMM + ReLU ------------------
__global__ __launch_bounds__(256, 4) void dcn_sample_mfma(
    const unsigned short* __restrict__ xT,
    const float* __restrict__ w_dcn,    // (32, 32, 3, 3)
    const float* __restrict__ off_ws,   // [18][NPIX]
    float* __restrict__ out)            // (8, 32, 160, 160)
{
    __shared__ __align__(16) unsigned short wl[9 * 2 * 64 * 8];
    const int tid = threadIdx.x;
    for (int d = tid; d < 9 * 1024; d += 256) {
        const int tap = d >> 10, r = d & 1023, o = r >> 5, c = r & 31;
        const int s = c >> 4, kg = (c >> 3) & 1;
        const int unit = (tap * 2 + s) * 64 + o + 32 * kg;
        wl[unit * 8 + (c & 7)] = bf16_rne(w_dcn[(o * 32 + c) * 9 + tap]);
    }
    __syncthreads();

    const int wave = tid >> 6, lane = tid & 63;
    const int n = lane & 31;
    const int hh = lane >> 5;
    const int pixbase = blockIdx.x * 128 + wave * 32;
    const int pix = pixbase + n;
    const int w = pix % W_, h = (pix / W_) % H_, b = pix / HW_;
    const unsigned short* __restrict__ xb = xT + (size_t)b * HW_ * 32 + hh * 8;

    f32x16 acc = {};

    #pragma unroll
    for (int tap = 0; tap < 9; ++tap) {
        const float dy = off_ws[(2 * tap) * NPIX + pix];
        const float dx = off_ws[(2 * tap + 1) * NPIX + pix];
        const float py = (float)(h - 1 + tap / 3) + dy;
        const float px = (float)(w - 1 + tap % 3) + dx;
        const float fy0 = floorf(py), fx0 = floorf(px);
        const float wy1 = py - fy0, wx1 = px - fx0;
        const float wy0 = 1.0f - wy1, wx0 = 1.0f - wx1;
        const int y0 = (int)fy0, x0 = (int)fx0;
        const bool vy0 = (y0 >= 0) && (y0 < H_);
        const bool vy1 = (y0 + 1 >= 0) && (y0 + 1 < H_);
        const bool vx0 = (x0 >= 0) && (x0 < W_);
        const bool vx1 = (x0 + 1 >= 0) && (x0 + 1 < W_);
        const float w00 = (vy0 && vx0) ? wy0 * wx0 : 0.0f;
        const float w01 = (vy0 && vx1) ? wy0 * wx1 : 0.0f;
        const float w10 = (vy1 && vx0) ? wy1 * wx0 : 0.0f;
        const float w11 = (vy1 && vx1) ? wy1 * wx1 : 0.0f;
        const int yc0 = min(max(y0, 0), H_ - 1), yc1 = min(max(y0 + 1, 0), H_ - 1);
        const int xc0 = min(max(x0, 0), W_ - 1), xc1 = min(max(x0 + 1, 0), W_ - 1);

        const unsigned short* __restrict__ pA = xb + (size_t)(yc0 * W_ + xc0) * 32;
        const unsigned short* __restrict__ pB = xb + (size_t)(yc0 * W_ + xc1) * 32;
        const unsigned short* __restrict__ pC = xb + (size_t)(yc1 * W_ + xc0) * 32;
        const unsigned short* __restrict__ pD = xb + (size_t)(yc1 * W_ + xc1) * 32;
        // 8 independent 16B gathers (2 k-steps x 4 corners)
        const u32x4 A0 = *(const u32x4*)(pA);      const u32x4 A1 = *(const u32x4*)(pA + 16);
        const u32x4 B0 = *(const u32x4*)(pB);      const u32x4 B1 = *(const u32x4*)(pB + 16);
        const u32x4 C0 = *(const u32x4*)(pC);      const u32x4 C1 = *(const u32x4*)(pC + 16);
        const u32x4 D0 = *(const u32x4*)(pD);      const u32x4 D1 = *(const u32x4*)(pD + 16);

        #define COMB(a, bb, cc, dd) ({ \
            const f32x2 v = up2(a) * w00 + up2(bb) * w01 + up2(cc) * w10 + up2(dd) * w11; \
            pack2_bf16(v.x, v.y); })
        u32x4 av0, av1;
        av0.x = COMB(A0.x, B0.x, C0.x, D0.x);
        av0.y = COMB(A0.y, B0.y, C0.y, D0.y);
        av0.z = COMB(A0.z, B0.z, C0.z, D0.z);
        av0.w = COMB(A0.w, B0.w, C0.w, D0.w);
        av1.x = COMB(A1.x, B1.x, C1.x, D1.x);
        av1.y = COMB(A1.y, B1.y, C1.y, D1.y);
        av1.z = COMB(A1.z, B1.z, C1.z, D1.z);
        av1.w = COMB(A1.w, B1.w, C1.w, D1.w);
        #undef COMB

        const short8 a0 = __builtin_bit_cast(short8, av0);
        const short8 a1 = __builtin_bit_cast(short8, av1);
        const short8 b0 = *(const short8*)(wl + ((tap * 2 + 0) * 64 + lane) * 8);
        const short8 b1 = *(const short8*)(wl + ((tap * 2 + 1) * 64 + lane) * 8);
        acc = __builtin_amdgcn_mfma_f32_32x32x16_bf16(a0, b0, acc, 0, 0, 0);
        acc = __builtin_amdgcn_mfma_f32_32x32x16_bf16(a1, b1, acc, 0, 0, 0);
    }

    // D: col o = n = lane&31; rows = pixels pixbase + g*8 + 4*hh + i
    float* __restrict__ ob = out + (size_t)b * 32 * HW_ + (size_t)n * HW_
                           + (pixbase - b * HW_) + 4 * hh;
    #pragma unroll
    for (int g = 0; g < 4; ++g) {
        f32x4 r;
        #pragma unroll
        for (int i = 0; i < 4; ++i) r[i] = fmaxf(acc[g * 4 + i], 0.0f);
        *(f32x4*)(ob + g * 8) = r;
    }
}

extern "C" void kernel_launch(void* const* d_in, const int* in_sizes, int n_in,
                              void* d_out, int out_size, void* d_ws, size_t ws_size,
                              hipStream_t stream) {
    const float* x     = (const float*)d_in[0];
    const float* w_off = (const float*)d_in[1];
    const float* b_off = (const float*)d_in[2];
    const float* w_dcn = (const float*)d_in[3];
    float* out = (float*)d_out;

    unsigned short* xT = (unsigned short*)d_ws;                    // 13.1 MB bf16 NHWC
    float* off_ws = (float*)((char*)d_ws + (size_t)NPIX * 32 * 2); // +14.75 MB fp32

    nhwc_bf16<<<800, 256, 0, stream>>>(x, xT);
    dcn_offset_mfma<<<1600, 256, 0, stream>>>(xT, w_off, b_off, off_ws);
    dcn_sample_mfma<<<1600, 256, 0, stream>>>(xT, w_dcn, off_ws, out);
}

// Round 11
// 157.857 us; speedup vs baseline: 2.2728x; 1.0115x over previous
//
#include <hip/hip_runtime.h>

#define H_ 160
#define W_ 160
#define HW_ (H_ * W_)
#define NPIX (8 * HW_)   // 204800 pixels

// ============================================================================
// R11: fused deformable conv, ALL-bf16 (R9-verified numerics; R10's fp16 MFMA
// path was the unproven variable in the failure -> reverted).
//  - single kernel: offset GEMM (mfma_32x32x16_bf16) -> per-wave LDS transpose
//    of D-layout offsets (row pad 33, conflict-free) -> bilinear sampling ->
//    dcn GEMM -> ReLU. Kills the 2x14.7MB off_ws round-trip + a launch.
//  - bilinear combine: R9's f32x2 packed math (v_pk_fma) + pack2_bf16.
// Layouts (verified m74/m101 + R9 pass): A[m=lane&31][k=(lane>>5)*8+j],
// B[n=lane&31][k=...], D: col n=lane&31, row=(reg&3)+8*(reg>>2)+4*(lane>>5).
// ============================================================================

typedef __attribute__((ext_vector_type(8)))  short  short8;   // 8 bf16
typedef __attribute__((ext_vector_type(4)))  float  f32x4;
typedef __attribute__((ext_vector_type(2)))  float  f32x2;
typedef __attribute__((ext_vector_type(16))) float  f32x16;
typedef __attribute__((ext_vector_type(4)))  unsigned u32x4;

__device__ __forceinline__ unsigned short bf16_rne(float f) {
    unsigned u = __float_as_uint(f);
    u += 0x7fffu + ((u >> 16) & 1u);
    return (unsigned short)(u >> 16);
}
__device__ __forceinline__ unsigned pack2_bf16(float a, float b) {
    unsigned ua = __float_as_uint(a); ua += 0x7fffu + ((ua >> 16) & 1u);
    unsigned ub = __float_as_uint(b); ub += 0x7fffu + ((ub >> 16) & 1u);
    return (ua >> 16) | (ub & 0xffff0000u);
}
__device__ __forceinline__ f32x2 up2(unsigned u) {
    f32x2 r;
    r.x = __uint_as_float(u << 16);
    r.y = __uint_as_float(u & 0xffff0000u);
    return r;
}

// ---- x (B,32,H,W) fp32 -> xT (B,H,W,32) bf16 (unchanged from R9) -----------
__global__ __launch_bounds__(256) void nhwc_bf16(
    const float* __restrict__ x, unsigned short* __restrict__ xT)
{
    const int pix = blockIdx.x * 256 + threadIdx.x;
    const int p = pix % HW_;
    const int b = pix / HW_;
    const float* __restrict__ src = x + (size_t)b * 32 * HW_ + p;
    unsigned* __restrict__ dst = (unsigned*)(xT + (size_t)pix * 32);
    #pragma unroll
    for (int g = 0; g < 16; ++g)
        dst[g] = pack2_bf16(src[(2 * g) * HW_], src[(2 * g + 1) * HW_]);
}

// ---- fused: offset conv + bilinear sampling + dcn GEMM + ReLU --------------
__global__ __launch_bounds__(256, 3) void dcn_fused(
    const unsigned short* __restrict__ xT,   // (8,160,160,32) bf16
    const float* __restrict__ w_off,         // (18, 32, 3, 3)
    const float* __restrict__ b_off,         // (18,)
    const float* __restrict__ w_dcn,         // (32, 32, 3, 3)
    float* __restrict__ out)                 // (8, 32, 160, 160)
{
    // lane-linear B-frags: unit = (tap*2 + kstep)*64 + lane, 8 bf16 each
    __shared__ __align__(16) unsigned short wo[9 * 2 * 64 * 8];  // offset conv
    __shared__ __align__(16) unsigned short wd[9 * 2 * 64 * 8];  // dcn
    __shared__ float offl[4 * 18 * 33];   // per-wave offset transpose, pad 33
    __shared__ float bl[32];
    const int tid = threadIdx.x;
    for (int d = tid; d < 9 * 1024; d += 256) {
        const int tap = d >> 10, r = d & 1023, j = r >> 5, c = r & 31;
        const int s = c >> 4, kg = (c >> 3) & 1;
        const int unit = (tap * 2 + s) * 64 + j + 32 * kg;
        wo[unit * 8 + (c & 7)] = (j < 18) ? bf16_rne(w_off[(j * 32 + c) * 9 + tap])
                                          : (unsigned short)0;
        wd[unit * 8 + (c & 7)] = bf16_rne(w_dcn[(j * 32 + c) * 9 + tap]);
    }
    if (tid < 32) bl[tid] = (tid < 18) ? b_off[tid] : 0.0f;
    __syncthreads();

    const int wave = tid >> 6, lane = tid & 63;
    const int n = lane & 31;          // pixel (A-row m) == out channel (D-col)
    const int hh = lane >> 5;         // k-group
    const int pixbase = blockIdx.x * 128 + wave * 32;
    const int pix = pixbase + n;
    const int w = pix % W_, h = (pix / W_) % H_, b = pix / HW_;
    const unsigned short* __restrict__ xb = xT + (size_t)b * HW_ * 32 + hh * 8;

    // ---------------- stage 1: offset conv GEMM (R9-verified) --------------
    {
        f32x16 acc = {};
        const u32x4 z4 = {0u, 0u, 0u, 0u};
        #pragma unroll
        for (int tap = 0; tap < 9; ++tap) {
            const int yy = h - 1 + tap / 3;
            const int xx = w - 1 + tap % 3;
            const bool valid = (yy >= 0) && (yy < H_) && (xx >= 0) && (xx < W_);
            const int idx = min(max(yy, 0), H_ - 1) * W_ + min(max(xx, 0), W_ - 1);
            const unsigned short* __restrict__ px_ = xb + (size_t)idx * 32;
            u32x4 l0 = *(const u32x4*)(px_);
            u32x4 l1 = *(const u32x4*)(px_ + 16);
            l0 = valid ? l0 : z4;
            l1 = valid ? l1 : z4;
            const short8 a0 = __builtin_bit_cast(short8, l0);
            const short8 a1 = __builtin_bit_cast(short8, l1);
            const short8 b0 = *(const short8*)(wo + ((tap * 2 + 0) * 64 + lane) * 8);
            const short8 b1 = *(const short8*)(wo + ((tap * 2 + 1) * 64 + lane) * 8);
            acc = __builtin_amdgcn_mfma_f32_32x32x16_bf16(a0, b0, acc, 0, 0, 0);
            acc = __builtin_amdgcn_mfma_f32_32x32x16_bf16(a1, b1, acc, 0, 0, 0);
        }
        // D-layout -> per-wave LDS transpose: [j(18)][pix(32)], row pad 33
        float* __restrict__ owp = offl + wave * 594;
        if (n < 18) {
            const float bia = bl[n];
            #pragma unroll
            for (int r = 0; r < 16; ++r) {
                const int prow = (r & 3) + 8 * (r >> 2) + 4 * hh;
                owp[n * 33 + prow] = acc[r] + bia;
            }
        }
    }
    __syncthreads();

    // ---------------- stage 2: bilinear sampling + dcn GEMM ----------------
    const float* __restrict__ ow = offl + wave * 594;
    f32x16 acc = {};

    #pragma unroll
    for (int tap = 0; tap < 9; ++tap) {
        const float dy = ow[(2 * tap) * 33 + n];
        const float dx = ow[(2 * tap + 1) * 33 + n];
        const float py = (float)(h - 1 + tap / 3) + dy;
        const float px = (float)(w - 1 + tap % 3) + dx;
        const float fy0 = floorf(py), fx0 = floorf(px);
        const float wy1 = py - fy0, wx1 = px - fx0;
        const float wy0 = 1.0f - wy1, wx0 = 1.0f - wx1;
        const int y0 = (int)fy0, x0 = (int)fx0;
        const bool vy0 = (y0 >= 0) && (y0 < H_);
        const bool vy1 = (y0 + 1 >= 0) && (y0 + 1 < H_);
        const bool vx0 = (x0 >= 0) && (x0 < W_);
        const bool vx1 = (x0 + 1 >= 0) && (x0 + 1 < W_);
        const float w00 = (vy0 && vx0) ? wy0 * wx0 : 0.0f;
        const float w01 = (vy0 && vx1) ? wy0 * wx1 : 0.0f;
        const float w10 = (vy1 && vx0) ? wy1 * wx0 : 0.0f;
        const float w11 = (vy1 && vx1) ? wy1 * wx1 : 0.0f;
        const int yc0 = min(max(y0, 0), H_ - 1), yc1 = min(max(y0 + 1, 0), H_ - 1);
        const int xc0 = min(max(x0, 0), W_ - 1), xc1 = min(max(x0 + 1, 0), W_ - 1);

        const unsigned short* __restrict__ pA = xb + (size_t)(yc0 * W_ + xc0) * 32;
        const unsigned short* __restrict__ pB = xb + (size_t)(yc0 * W_ + xc1) * 32;
        const unsigned short* __restrict__ pC = xb + (size_t)(yc1 * W_ + xc0) * 32;
        const unsigned short* __restrict__ pD = xb + (size_t)(yc1 * W_ + xc1) * 32;
        // 8 independent 16B gathers (2 k-steps x 4 corners)
        const u32x4 A0 = *(const u32x4*)(pA);      const u32x4 A1 = *(const u32x4*)(pA + 16);
        const u32x4 B0 = *(const u32x4*)(pB);      const u32x4 B1 = *(const u32x4*)(pB + 16);
        const u32x4 C0 = *(const u32x4*)(pC);      const u32x4 C1 = *(const u32x4*)(pC + 16);
        const u32x4 D0 = *(const u32x4*)(pD);      const u32x4 D1 = *(const u32x4*)(pD + 16);

        // R9-verified packed-fp32 bilinear combine
        #define COMB(a, bb, cc, dd) ({ \
            const f32x2 v = up2(a) * w00 + up2(bb) * w01 + up2(cc) * w10 + up2(dd) * w11; \
            pack2_bf16(v.x, v.y); })
        u32x4 av0, av1;
        av0.x = COMB(A0.x, B0.x, C0.x, D0.x);
        av0.y = COMB(A0.y, B0.y, C0.y, D0.y);
        av0.z = COMB(A0.z, B0.z, C0.z, D0.z);
        av0.w = COMB(A0.w, B0.w, C0.w, D0.w);
        av1.x = COMB(A1.x, B1.x, C1.x, D1.x);
        av1.y = COMB(A1.y, B1.y, C1.y, D1.y);
        av1.z = COMB(A1.z, B1.z, C1.z, D1.z);
        av1.w = COMB(A1.w, B1.w, C1.w, D1.w);
        #undef COMB

        const short8 a0 = __builtin_bit_cast(short8, av0);
        const short8 a1 = __builtin_bit_cast(short8, av1);
        const short8 b0 = *(const short8*)(wd + ((tap * 2 + 0) * 64 + lane) * 8);
        const short8 b1 = *(const short8*)(wd + ((tap * 2 + 1) * 64 + lane) * 8);
        acc = __builtin_amdgcn_mfma_f32_32x32x16_bf16(a0, b0, acc, 0, 0, 0);
        acc = __builtin_amdgcn_mfma_f32_32x32x16_bf16(a1, b1, acc, 0, 0, 0);
    }

    // D: col o = n; rows = pixels pixbase + g*8 + 4*hh + i
    float* __restrict__ ob = out + (size_t)b * 32 * HW_ + (size_t)n * HW_
                           + (pixbase - b * HW_) + 4 * hh;
    #pragma unroll
    for (int g = 0; g < 4; ++g) {
        f32x4 r;
        #pragma unroll
        for (int i = 0; i < 4; ++i) r[i] = fmaxf(acc[g * 4 + i], 0.0f);
        *(f32x4*)(ob + g * 8) = r;
    }
}

extern "C" void kernel_launch(void* const* d_in, const int* in_sizes, int n_in,
                              void* d_out, int out_size, void* d_ws, size_t ws_size,
                              hipStream_t stream) {
    const float* x     = (const float*)d_in[0];
    const float* w_off = (const float*)d_in[1];
    const float* b_off = (const float*)d_in[2];
    const float* w_dcn = (const float*)d_in[3];
    float* out = (float*)d_out;

    unsigned short* xT = (unsigned short*)d_ws;   // 13.1 MB bf16 NHWC

    nhwc_bf16<<<800, 256, 0, stream>>>(x, xT);
    dcn_fused<<<1600, 256, 0, stream>>>(xT, w_off, b_off, w_dcn, out);
}